// Round 1
// baseline (431.375 us; speedup 1.0000x reference)
//
#include <hip/hip_runtime.h>

#define NN 100000
#define NE 600000
#define D 128
#define NREL 16

typedef short short8 __attribute__((ext_vector_type(8)));
typedef float f32x4 __attribute__((ext_vector_type(4)));

// meta layout (ints)
#define C0 0    // counts[17]
#define O0 20   // offsets[18]
#define CU0 40  // cursors[17]
#define T0 60   // tileoff[18]

#define WT_ELEMS (17 * 128 * 128)
#define META_OFF (WT_ELEMS * 2)          // 557056 bytes
#define SC_OFF (META_OFF + 512)
#define SR_OFF (SC_OFF + 700000 * 4)

__device__ __forceinline__ unsigned short f2bf(float f) {
  unsigned u = __builtin_bit_cast(unsigned, f);
  u += 0x7fffu + ((u >> 16) & 1u);   // RNE; inputs are finite/normal
  return (unsigned short)(u >> 16);
}

// wT[r][o][i] = sum_b coef[r,b] * bases[b][i][o]  (bf16); slot 16 = w_self (already [o][i])
__global__ __launch_bounds__(256) void k_weights(const float* __restrict__ bases,
    const float* __restrict__ coef, const float* __restrict__ w_self,
    unsigned short* __restrict__ wT)
{
  int idx = blockIdx.x * 256 + threadIdx.x;   // < 17*16384
  int r = idx >> 14;
  int t = idx & 16383;
  float v;
  if (r < 16) {
    int o = t >> 7, i = t & 127;
    float acc = 0.f;
    #pragma unroll
    for (int b = 0; b < 8; ++b)
      acc += coef[r * 8 + b] * bases[b * 16384 + i * 128 + o];
    v = acc;
  } else {
    v = w_self[t];
  }
  wT[idx] = f2bf(v);
}

__global__ __launch_bounds__(256) void k_hist(const int* __restrict__ et, int* __restrict__ meta)
{
  __shared__ int h[16];
  int tid = threadIdx.x;
  if (tid < 16) h[tid] = 0;
  __syncthreads();
  for (int e = blockIdx.x * 256 + tid; e < NE; e += gridDim.x * 256)
    atomicAdd(&h[et[e]], 1);
  __syncthreads();
  if (tid < 16) atomicAdd(&meta[C0 + tid], h[tid]);
}

__global__ void k_prefix(int* meta)
{
  meta[C0 + 16] = NN;                 // virtual self-loop bucket
  int off = 0, toff = 0;
  for (int r = 0; r <= 16; ++r) {
    meta[O0 + r] = off;
    meta[CU0 + r] = off;
    meta[T0 + r] = toff;
    int c = meta[C0 + r];
    off += c;
    toff += (c + 63) >> 6;
  }
  meta[O0 + 17] = off;
  meta[T0 + 17] = toff;
}

__global__ __launch_bounds__(256) void k_scatter(const int* __restrict__ ei, const int* __restrict__ et,
    int* __restrict__ meta, int* __restrict__ sCol, int* __restrict__ sRow)
{
  __shared__ int h[16], base[16], lh[16];
  int tid = threadIdx.x;
  int start = blockIdx.x * 4096;
  int end = min(NE, start + 4096);
  if (tid < 16) { h[tid] = 0; lh[tid] = 0; }
  __syncthreads();
  for (int e = start + tid; e < end; e += 256)
    atomicAdd(&h[et[e]], 1);
  __syncthreads();
  if (tid < 16) base[tid] = atomicAdd(&meta[CU0 + tid], h[tid]);
  __syncthreads();
  for (int e = start + tid; e < end; e += 256) {
    int r = et[e];
    int pos = base[r] + atomicAdd(&lh[r], 1);
    sCol[pos] = ei[NE + e];   // source (gather)
    sRow[pos] = ei[e];        // destination (scatter)
  }
}

__global__ __launch_bounds__(256) void k_self(int* __restrict__ sCol, int* __restrict__ sRow)
{
  int n = blockIdx.x * 256 + threadIdx.x;
  if (n < NN) { sCol[NE + n] = n; sRow[NE + n] = n; }
}

// One 64-edge x 128-out tile per block. A: gathered x rows (bf16, LDS, padded units).
// B: wT[r] fragments in registers. D-layout: col=lane&15, row=quad*4+reg.
__global__ __launch_bounds__(256) void k_gemm(const float* __restrict__ x,
    const unsigned short* __restrict__ wT, const int* __restrict__ meta,
    const int* __restrict__ sCol, const int* __restrict__ sRow,
    float* __restrict__ out)
{
  __shared__ short As[64 * 17 * 8];   // 64 rows x (16+1 pad) units x 8 bf16 = 17408 B
  __shared__ int Rows[64];
  int b = blockIdx.x;
  if (b >= meta[T0 + 17]) return;
  int r = 0;
  while (r < 16 && meta[T0 + r + 1] <= b) ++r;
  int tile = b - meta[T0 + r];
  int boff = meta[O0 + r];
  int bcnt = meta[C0 + r];
  int e0 = boff + tile * 64;
  int nrows = min(64, boff + bcnt - e0);

  int tid = threadIdx.x;
  int lane = tid & 63, wave = tid >> 6;
  int q = lane >> 4, l15 = lane & 15;

  // B fragments: wave owns cols [wave*32, wave*32+32); b[n][k]: n=lane&15, k=q*8+j
  const unsigned short* wr = wT + r * 16384;
  short8 bf[2][4];
  #pragma unroll
  for (int ns = 0; ns < 2; ++ns) {
    #pragma unroll
    for (int kk = 0; kk < 4; ++kk) {
      int n = wave * 32 + ns * 16 + l15;
      bf[ns][kk] = *(const short8*)(wr + n * 128 + kk * 32 + q * 8);
    }
  }

  // Stage A: thread t -> row m = t>>2, quarter ug = t&3 covers k in [ug*32, ug*32+32)
  int m = tid >> 2, ug = tid & 3;
  bool valid = m < nrows;
  int c = valid ? sCol[e0 + m] : 0;
  const float* xr = x + c * 128;
  #pragma unroll
  for (int s = 0; s < 4; ++s) {
    int u = ug * 4 + s;                       // unit u holds k in [8u, 8u+8)
    float4 f0 = make_float4(0.f, 0.f, 0.f, 0.f), f1 = f0;
    if (valid) {
      f0 = *(const float4*)(xr + u * 8);
      f1 = *(const float4*)(xr + u * 8 + 4);
    }
    short8 pk;
    pk[0] = (short)f2bf(f0.x); pk[1] = (short)f2bf(f0.y);
    pk[2] = (short)f2bf(f0.z); pk[3] = (short)f2bf(f0.w);
    pk[4] = (short)f2bf(f1.x); pk[5] = (short)f2bf(f1.y);
    pk[6] = (short)f2bf(f1.z); pk[7] = (short)f2bf(f1.w);
    *(short8*)&As[(m * 17 + u) * 8] = pk;
  }
  if (tid < 64) Rows[tid] = (tid < nrows) ? sRow[e0 + tid] : 0;
  __syncthreads();

  f32x4 acc[4][2];
  #pragma unroll
  for (int ms = 0; ms < 4; ++ms)
    #pragma unroll
    for (int ns = 0; ns < 2; ++ns)
      acc[ms][ns] = (f32x4){0.f, 0.f, 0.f, 0.f};

  #pragma unroll
  for (int kk = 0; kk < 4; ++kk) {
    short8 af[4];
    #pragma unroll
    for (int ms = 0; ms < 4; ++ms)
      af[ms] = *(const short8*)&As[((ms * 16 + l15) * 17 + kk * 4 + q) * 8];
    #pragma unroll
    for (int ms = 0; ms < 4; ++ms)
      #pragma unroll
      for (int ns = 0; ns < 2; ++ns)
        acc[ms][ns] = __builtin_amdgcn_mfma_f32_16x16x32_bf16(af[ms], bf[ns][kk], acc[ms][ns], 0, 0, 0);
  }

  // Epilogue: scatter-add. D: col = lane&15, row = q*4 + reg.
  #pragma unroll
  for (int ms = 0; ms < 4; ++ms) {
    #pragma unroll
    for (int reg = 0; reg < 4; ++reg) {
      int mrow = ms * 16 + q * 4 + reg;
      if (mrow < nrows) {
        int dst = Rows[mrow];
        float* op = out + dst * 128 + wave * 32 + l15;
        unsafeAtomicAdd(op, acc[ms][0][reg]);
        unsafeAtomicAdd(op + 16, acc[ms][1][reg]);
      }
    }
  }
}

extern "C" void kernel_launch(void* const* d_in, const int* in_sizes, int n_in,
                              void* d_out, int out_size, void* d_ws, size_t ws_size,
                              hipStream_t stream)
{
  const float* x      = (const float*)d_in[0];
  const int*   ei     = (const int*)d_in[1];
  const int*   et     = (const int*)d_in[2];
  const float* bases  = (const float*)d_in[3];
  const float* coef   = (const float*)d_in[4];
  const float* w_self = (const float*)d_in[5];
  float* out = (float*)d_out;
  char* ws = (char*)d_ws;
  unsigned short* wT = (unsigned short*)ws;
  int* meta = (int*)(ws + META_OFF);
  int* sCol = (int*)(ws + SC_OFF);
  int* sRow = (int*)(ws + SR_OFF);

  hipMemsetAsync(d_out, 0, (size_t)NN * D * 4, stream);
  hipMemsetAsync(meta, 0, 512, stream);
  k_weights<<<(17 * 16384) / 256, 256, 0, stream>>>(bases, coef, w_self, wT);
  k_hist<<<256, 256, 0, stream>>>(et, meta);
  k_self<<<(NN + 255) / 256, 256, 0, stream>>>(sCol, sRow);
  k_prefix<<<1, 1, 0, stream>>>(meta);
  k_scatter<<<(NE + 4095) / 4096, 256, 0, stream>>>(ei, et, meta, sCol, sRow);
  // max tiles: ceil(600000/64)+15 + ceil(100000/64) = 9390 + 1563 = 10953 (+1 slack)
  k_gemm<<<10954, 256, 0, stream>>>(x, wT, meta, sCol, sRow, out);
}

// Round 2
// 396.441 us; speedup vs baseline: 1.0881x; 1.0881x over previous
//
#include <hip/hip_runtime.h>

#define NN 100000
#define NE 600000
#define ET (NE + NN)
#define D 128
#define NREL 16
#define SCANB 391   // 391*256 = 100096 >= NN

typedef short short8 __attribute__((ext_vector_type(8)));
typedef float f32x4 __attribute__((ext_vector_type(4)));

// meta layout (ints)
#define C0 0    // counts[17]
#define O0 20   // offsets[18]
#define CU0 40  // cursors[17]
#define T0 60   // tileoff[18]

// ws layout (bytes)
#define WT_OFF 0
#define META_OFF 557056
#define DH_OFF   557568           // dstHist: 100000 ints
#define DO_OFF   957568           // dstOff: 100001 ints
#define DC_OFF   1357576          // dstCursor: 100000 ints
#define BS_OFF   1757576          // blockSums: 391 ints
#define SC_OFF   1759168          // sCol: 700000 ints
#define SR_OFF   4559168          // sRow: 700000 ints
#define MP_OFF   7359168          // mpos: 700000 ints
#define MSG_OFF  10159168         // msg: 700000*128 bf16 = 179.2 MB
#define NEED_A   (MSG_OFF + (size_t)ET * 128 * 2)

__device__ __forceinline__ unsigned short f2bf(float f) {
  unsigned u = __builtin_bit_cast(unsigned, f);
  u += 0x7fffu + ((u >> 16) & 1u);   // RNE; inputs finite/normal
  return (unsigned short)(u >> 16);
}

// wT[r][o][i] = sum_b coef[r,b] * bases[b][i][o]  (bf16); slot 16 = w_self ([o][i])
__global__ __launch_bounds__(256) void k_weights(const float* __restrict__ bases,
    const float* __restrict__ coef, const float* __restrict__ w_self,
    unsigned short* __restrict__ wT)
{
  int idx = blockIdx.x * 256 + threadIdx.x;   // < 17*16384
  int r = idx >> 14;
  int t = idx & 16383;
  float v;
  if (r < 16) {
    int o = t >> 7, i = t & 127;
    float acc = 0.f;
    #pragma unroll
    for (int b = 0; b < 8; ++b)
      acc += coef[r * 8 + b] * bases[b * 16384 + i * 128 + o];
    v = acc;
  } else {
    v = w_self[t];
  }
  wT[idx] = f2bf(v);
}

// rel histogram (LDS) + dst histogram (global atomics)
__global__ __launch_bounds__(256) void k_hist(const int* __restrict__ ei,
    const int* __restrict__ et, int* __restrict__ meta, int* __restrict__ dstHist)
{
  __shared__ int h[16];
  int tid = threadIdx.x;
  if (tid < 16) h[tid] = 0;
  __syncthreads();
  for (int e = blockIdx.x * 256 + tid; e < NE; e += gridDim.x * 256) {
    atomicAdd(&h[et[e]], 1);
    atomicAdd(&dstHist[ei[e]], 1);
  }
  __syncthreads();
  if (tid < 16) atomicAdd(&meta[C0 + tid], h[tid]);
}

// per-256-block local exclusive prefix of (dstHist[d]+1); block totals out
__global__ __launch_bounds__(256) void k_scan1(const int* __restrict__ dstHist,
    int* __restrict__ dstOff, int* __restrict__ blockSums)
{
  __shared__ int sh[256];
  int tid = threadIdx.x;
  int d = blockIdx.x * 256 + tid;
  int v = (d < NN) ? (dstHist[d] + 1) : 0;   // +1: virtual self edge
  sh[tid] = v;
  __syncthreads();
  #pragma unroll
  for (int ofs = 1; ofs < 256; ofs <<= 1) {
    int t = (tid >= ofs) ? sh[tid - ofs] : 0;
    __syncthreads();
    sh[tid] += t;
    __syncthreads();
  }
  if (d < NN) dstOff[d] = sh[tid] - v;       // local exclusive
  if (tid == 255) blockSums[blockIdx.x] = sh[tid];
}

// scan block totals; also fold the rel-prefix (old k_prefix)
__global__ __launch_bounds__(512) void k_scan2(int* __restrict__ blockSums, int* __restrict__ meta)
{
  __shared__ int sh[SCANB];
  int tid = threadIdx.x;
  if (tid < SCANB) sh[tid] = blockSums[tid];
  __syncthreads();
  if (tid == 0) {
    int run = 0;
    for (int i = 0; i < SCANB; ++i) { int c = sh[i]; sh[i] = run; run += c; }
    meta[C0 + 16] = NN;
    int off = 0, toff = 0;
    for (int r = 0; r <= 16; ++r) {
      meta[O0 + r] = off;
      meta[CU0 + r] = off;
      meta[T0 + r] = toff;
      int c = meta[C0 + r];
      off += c;
      toff += (c + 63) >> 6;
    }
    meta[O0 + 17] = off;
    meta[T0 + 17] = toff;
  }
  __syncthreads();
  if (tid < SCANB) blockSums[tid] = sh[tid];
}

__global__ __launch_bounds__(256) void k_scan3(int* __restrict__ dstOff,
    const int* __restrict__ blockSums, int* __restrict__ dstCursor)
{
  int tid = threadIdx.x;
  int d = blockIdx.x * 256 + tid;
  int base = blockSums[blockIdx.x];
  if (d < NN) {
    int o = dstOff[d] + base;
    dstOff[d] = o;
    dstCursor[d] = o;
  }
  if (d == NN) dstOff[NN] = ET;
}

__global__ __launch_bounds__(256) void k_self(int* __restrict__ sCol, int* __restrict__ sRow,
    int* __restrict__ mpos, int* __restrict__ dstCursor, int doMsg)
{
  int n = blockIdx.x * 256 + threadIdx.x;
  if (n < NN) {
    sCol[NE + n] = n;
    sRow[NE + n] = n;
    if (doMsg) mpos[NE + n] = atomicAdd(&dstCursor[n], 1);
  }
}

__global__ __launch_bounds__(256) void k_scatter(const int* __restrict__ ei, const int* __restrict__ et,
    int* __restrict__ meta, int* __restrict__ sCol, int* __restrict__ sRow,
    int* __restrict__ mpos, int* __restrict__ dstCursor, int doMsg)
{
  __shared__ int h[16], base[16], lh[16];
  int tid = threadIdx.x;
  int start = blockIdx.x * 4096;
  int end = min(NE, start + 4096);
  if (tid < 16) { h[tid] = 0; lh[tid] = 0; }
  __syncthreads();
  for (int e = start + tid; e < end; e += 256)
    atomicAdd(&h[et[e]], 1);
  __syncthreads();
  if (tid < 16) base[tid] = atomicAdd(&meta[CU0 + tid], h[tid]);
  __syncthreads();
  for (int e = start + tid; e < end; e += 256) {
    int r = et[e];
    int row = ei[e];
    int pos = base[r] + atomicAdd(&lh[r], 1);
    sCol[pos] = ei[NE + e];   // source (gather)
    sRow[pos] = row;          // destination
    if (doMsg) mpos[pos] = atomicAdd(&dstCursor[row], 1);
  }
}

// One 64-edge x 128-out tile per block. A: gathered x rows (bf16, LDS, padded units).
// B: wT[r] fragments in registers. D-layout: col=lane&15, row=quad*4+reg.
// mode 1: write bf16 msg rows at dst-sorted slots (no atomics).
// mode 0: fallback, atomic scatter-add into out.
__global__ __launch_bounds__(256) void k_gemm(const float* __restrict__ x,
    const unsigned short* __restrict__ wT, const int* __restrict__ meta,
    const int* __restrict__ sCol, const int* __restrict__ sRow,
    const int* __restrict__ mpos, unsigned short* __restrict__ msg,
    float* __restrict__ out, int mode)
{
  __shared__ short As[64 * 17 * 8];   // 17408 B
  __shared__ int Rows[64];
  __shared__ int Pos[64];
  int b = blockIdx.x;
  if (b >= meta[T0 + 17]) return;
  int r = 0;
  while (r < 16 && meta[T0 + r + 1] <= b) ++r;
  int tile = b - meta[T0 + r];
  int boff = meta[O0 + r];
  int bcnt = meta[C0 + r];
  int e0 = boff + tile * 64;
  int nrows = min(64, boff + bcnt - e0);

  int tid = threadIdx.x;
  int lane = tid & 63, wave = tid >> 6;
  int q = lane >> 4, l15 = lane & 15;

  // B fragments: wave owns cols [wave*32, wave*32+32)
  const unsigned short* wr = wT + r * 16384;
  short8 bf[2][4];
  #pragma unroll
  for (int ns = 0; ns < 2; ++ns) {
    #pragma unroll
    for (int kk = 0; kk < 4; ++kk) {
      int n = wave * 32 + ns * 16 + l15;
      bf[ns][kk] = *(const short8*)(wr + n * 128 + kk * 32 + q * 8);
    }
  }

  // Stage A: thread t -> row m = t>>2, quarter ug = t&3
  int m = tid >> 2, ug = tid & 3;
  bool valid = m < nrows;
  int c = valid ? sCol[e0 + m] : 0;
  const float* xr = x + c * 128;
  #pragma unroll
  for (int s = 0; s < 4; ++s) {
    int u = ug * 4 + s;
    float4 f0 = make_float4(0.f, 0.f, 0.f, 0.f), f1 = f0;
    if (valid) {
      f0 = *(const float4*)(xr + u * 8);
      f1 = *(const float4*)(xr + u * 8 + 4);
    }
    short8 pk;
    pk[0] = (short)f2bf(f0.x); pk[1] = (short)f2bf(f0.y);
    pk[2] = (short)f2bf(f0.z); pk[3] = (short)f2bf(f0.w);
    pk[4] = (short)f2bf(f1.x); pk[5] = (short)f2bf(f1.y);
    pk[6] = (short)f2bf(f1.z); pk[7] = (short)f2bf(f1.w);
    *(short8*)&As[(m * 17 + u) * 8] = pk;
  }
  if (tid < 64) {
    Rows[tid] = (tid < nrows) ? sRow[e0 + tid] : 0;
    Pos[tid] = (mode && tid < nrows) ? mpos[e0 + tid] : 0;
  }
  __syncthreads();

  f32x4 acc[4][2];
  #pragma unroll
  for (int ms = 0; ms < 4; ++ms)
    #pragma unroll
    for (int ns = 0; ns < 2; ++ns)
      acc[ms][ns] = (f32x4){0.f, 0.f, 0.f, 0.f};

  #pragma unroll
  for (int kk = 0; kk < 4; ++kk) {
    short8 af[4];
    #pragma unroll
    for (int ms = 0; ms < 4; ++ms)
      af[ms] = *(const short8*)&As[((ms * 16 + l15) * 17 + kk * 4 + q) * 8];
    #pragma unroll
    for (int ms = 0; ms < 4; ++ms)
      #pragma unroll
      for (int ns = 0; ns < 2; ++ns)
        acc[ms][ns] = __builtin_amdgcn_mfma_f32_16x16x32_bf16(af[ms], bf[ns][kk], acc[ms][ns], 0, 0, 0);
  }

  // Epilogue. D: col = lane&15, row = q*4 + reg.
  if (mode) {
    #pragma unroll
    for (int ms = 0; ms < 4; ++ms) {
      #pragma unroll
      for (int reg = 0; reg < 4; ++reg) {
        int mrow = ms * 16 + q * 4 + reg;
        if (mrow < nrows) {
          unsigned short* mp = msg + (size_t)Pos[mrow] * 128 + wave * 32 + l15;
          mp[0]  = f2bf(acc[ms][0][reg]);
          mp[16] = f2bf(acc[ms][1][reg]);
        }
      }
    }
  } else {
    #pragma unroll
    for (int ms = 0; ms < 4; ++ms) {
      #pragma unroll
      for (int reg = 0; reg < 4; ++reg) {
        int mrow = ms * 16 + q * 4 + reg;
        if (mrow < nrows) {
          float* op = out + (size_t)Rows[mrow] * 128 + wave * 32 + l15;
          unsafeAtomicAdd(op, acc[ms][0][reg]);
          unsafeAtomicAdd(op + 16, acc[ms][1][reg]);
        }
      }
    }
  }
}

// one wave per dst row: stream contiguous msg segment, accumulate fp32, write once
__global__ __launch_bounds__(256) void k_reduce(const unsigned short* __restrict__ msg,
    const int* __restrict__ dstOff, float* __restrict__ out)
{
  int d = blockIdx.x * 4 + (threadIdx.x >> 6);
  if (d >= NN) return;
  int lane = threadIdx.x & 63;
  int s = dstOff[d], e = dstOff[d + 1];
  float a0 = 0.f, a1 = 0.f;
  const unsigned int* base = (const unsigned int*)msg;
  for (int j = s; j < e; ++j) {
    unsigned int v = base[(size_t)j * 64 + lane];
    a0 += __builtin_bit_cast(float, v << 16);
    a1 += __builtin_bit_cast(float, v & 0xffff0000u);
  }
  float2 w; w.x = a0; w.y = a1;
  *(float2*)(out + (size_t)d * 128 + lane * 2) = w;
}

extern "C" void kernel_launch(void* const* d_in, const int* in_sizes, int n_in,
                              void* d_out, int out_size, void* d_ws, size_t ws_size,
                              hipStream_t stream)
{
  const float* x      = (const float*)d_in[0];
  const int*   ei     = (const int*)d_in[1];
  const int*   et     = (const int*)d_in[2];
  const float* bases  = (const float*)d_in[3];
  const float* coef   = (const float*)d_in[4];
  const float* w_self = (const float*)d_in[5];
  float* out = (float*)d_out;
  char* ws = (char*)d_ws;
  unsigned short* wT = (unsigned short*)(ws + WT_OFF);
  int* meta      = (int*)(ws + META_OFF);
  int* dstHist   = (int*)(ws + DH_OFF);
  int* dstOff    = (int*)(ws + DO_OFF);
  int* dstCursor = (int*)(ws + DC_OFF);
  int* blockSums = (int*)(ws + BS_OFF);
  int* sCol      = (int*)(ws + SC_OFF);
  int* sRow      = (int*)(ws + SR_OFF);
  int* mpos      = (int*)(ws + MP_OFF);
  unsigned short* msg = (unsigned short*)(ws + MSG_OFF);

  const int modeA = (ws_size >= NEED_A) ? 1 : 0;   // constant per problem -> graph-safe

  // zero rel meta + dst histogram in one memset (contiguous)
  hipMemsetAsync(ws + META_OFF, 0, 512 + 400000, stream);
  k_weights<<<(17 * 16384) / 256, 256, 0, stream>>>(bases, coef, w_self, wT);
  k_hist<<<256, 256, 0, stream>>>(ei, et, meta, dstHist);
  if (modeA) {
    k_scan1<<<SCANB, 256, 0, stream>>>(dstHist, dstOff, blockSums);
    k_scan2<<<1, 512, 0, stream>>>(blockSums, meta);
    k_scan3<<<SCANB, 256, 0, stream>>>(dstOff, blockSums, dstCursor);
  } else {
    k_scan2<<<1, 512, 0, stream>>>(blockSums, meta);   // rel prefix only (blockSums unused)
    hipMemsetAsync(d_out, 0, (size_t)NN * D * 4, stream);
  }
  k_self<<<SCANB, 256, 0, stream>>>(sCol, sRow, mpos, dstCursor, modeA);
  k_scatter<<<(NE + 4095) / 4096, 256, 0, stream>>>(ei, et, meta, sCol, sRow, mpos, dstCursor, modeA);
  // max tiles: sum_r ceil(c_r/64) + ceil(NN/64) <= 9391 + 1563 = 10954
  k_gemm<<<10954, 256, 0, stream>>>(x, wT, meta, sCol, sRow, mpos, msg, out, modeA);
  if (modeA)
    k_reduce<<<(NN + 3) / 4, 256, 0, stream>>>(msg, dstOff, out);
}

// Round 3
// 391.495 us; speedup vs baseline: 1.1019x; 1.0126x over previous
//
#include <hip/hip_runtime.h>

#define NN 100000
#define NE 600000
#define ET (NE + NN)
#define D 128
#define NREL 16
#define SCANB 391   // 391*256 = 100096 >= NN

typedef short short8 __attribute__((ext_vector_type(8)));
typedef float f32x4 __attribute__((ext_vector_type(4)));

// meta layout (ints)
#define C0 0    // counts[17]
#define O0 20   // offsets[18]
#define CU0 40  // cursors[17]
#define T0 60   // tileoff[18]

// ws layout (bytes)
#define WT_OFF 0
#define META_OFF 557056
#define DH_OFF   557568           // dstHist: 100000 ints
#define DO_OFF   957568           // dstOff: 100001 ints
#define DC_OFF   1357576          // dstCursor: 100000 ints
#define BS_OFF   1759168          // blockSums: 391 ints
#define SC_OFF   1761168          // sCol: 700000 ints
#define SR_OFF   4561168          // sRow: 700000 ints
#define MP_OFF   7361168          // mpos: 700000 ints
#define XB_OFF   10161168         // xb: 100000*128 bf16 = 25.6 MB
#define MSGB_OFF 35761168         // msg (mode B)
#define MSGA_OFF 10161168         // msg (mode A, no xb)
#define NEED_B   (MSGB_OFF + (size_t)ET * 128 * 2)
#define NEED_A   (MSGA_OFF + (size_t)ET * 128 * 2)

__device__ __forceinline__ unsigned short f2bf(float f) {
  unsigned u = __builtin_bit_cast(unsigned, f);
  u += 0x7fffu + ((u >> 16) & 1u);   // RNE; inputs finite/normal
  return (unsigned short)(u >> 16);
}

// wT[r][o][i] = sum_b coef[r,b] * bases[b][i][o]  (bf16); slot 16 = w_self ([o][i])
__global__ __launch_bounds__(256) void k_weights(const float* __restrict__ bases,
    const float* __restrict__ coef, const float* __restrict__ w_self,
    unsigned short* __restrict__ wT)
{
  int idx = blockIdx.x * 256 + threadIdx.x;   // < 17*16384
  int r = idx >> 14;
  int t = idx & 16383;
  float v;
  if (r < 16) {
    int o = t >> 7, i = t & 127;
    float acc = 0.f;
    #pragma unroll
    for (int b = 0; b < 8; ++b)
      acc += coef[r * 8 + b] * bases[b * 16384 + i * 128 + o];
    v = acc;
  } else {
    v = w_self[t];
  }
  wT[idx] = f2bf(v);
}

// x (fp32) -> xb (bf16), 4 elems/thread. Same RNE rounding as the old in-gemm path.
__global__ __launch_bounds__(256) void k_xcast(const float* __restrict__ x,
    unsigned short* __restrict__ xb)
{
  int i = blockIdx.x * 256 + threadIdx.x;   // < NN*D/4
  if (i >= NN * D / 4) return;
  float4 f = *(const float4*)(x + (size_t)i * 4);
  short8 dummy;
  unsigned short s0 = f2bf(f.x), s1 = f2bf(f.y), s2 = f2bf(f.z), s3 = f2bf(f.w);
  (void)dummy;
  unsigned long long pk = (unsigned long long)s0 | ((unsigned long long)s1 << 16)
                        | ((unsigned long long)s2 << 32) | ((unsigned long long)s3 << 48);
  *(unsigned long long*)(xb + (size_t)i * 4) = pk;
}

// rel histogram (LDS) + dst histogram (global atomics)
__global__ __launch_bounds__(256) void k_hist(const int* __restrict__ ei,
    const int* __restrict__ et, int* __restrict__ meta, int* __restrict__ dstHist)
{
  __shared__ int h[16];
  int tid = threadIdx.x;
  if (tid < 16) h[tid] = 0;
  __syncthreads();
  for (int e = blockIdx.x * 256 + tid; e < NE; e += gridDim.x * 256) {
    atomicAdd(&h[et[e]], 1);
    atomicAdd(&dstHist[ei[e]], 1);
  }
  __syncthreads();
  if (tid < 16) atomicAdd(&meta[C0 + tid], h[tid]);
}

// per-256-block local exclusive prefix of (dstHist[d]+1); block totals out
__global__ __launch_bounds__(256) void k_scan1(const int* __restrict__ dstHist,
    int* __restrict__ dstOff, int* __restrict__ blockSums)
{
  __shared__ int sh[256];
  int tid = threadIdx.x;
  int d = blockIdx.x * 256 + tid;
  int v = (d < NN) ? (dstHist[d] + 1) : 0;   // +1: virtual self edge
  sh[tid] = v;
  __syncthreads();
  #pragma unroll
  for (int ofs = 1; ofs < 256; ofs <<= 1) {
    int t = (tid >= ofs) ? sh[tid - ofs] : 0;
    __syncthreads();
    sh[tid] += t;
    __syncthreads();
  }
  if (d < NN) dstOff[d] = sh[tid] - v;       // local exclusive
  if (tid == 255) blockSums[blockIdx.x] = sh[tid];
}

// scan block totals; also fold the rel-prefix
__global__ __launch_bounds__(512) void k_scan2(int* __restrict__ blockSums, int* __restrict__ meta)
{
  __shared__ int sh[SCANB];
  int tid = threadIdx.x;
  if (tid < SCANB) sh[tid] = blockSums[tid];
  __syncthreads();
  if (tid == 0) {
    int run = 0;
    for (int i = 0; i < SCANB; ++i) { int c = sh[i]; sh[i] = run; run += c; }
    meta[C0 + 16] = NN;
    int off = 0, toff = 0;
    for (int r = 0; r <= 16; ++r) {
      meta[O0 + r] = off;
      meta[CU0 + r] = off;
      meta[T0 + r] = toff;
      int c = meta[C0 + r];
      off += c;
      toff += (c + 63) >> 6;
    }
    meta[O0 + 17] = off;
    meta[T0 + 17] = toff;
  }
  __syncthreads();
  if (tid < SCANB) blockSums[tid] = sh[tid];
}

// finalize dstOff; self edge claims slot 0 of each segment (no atomics);
// cursor starts after it.
__global__ __launch_bounds__(256) void k_scan3(int* __restrict__ dstOff,
    const int* __restrict__ blockSums, int* __restrict__ dstCursor,
    int* __restrict__ sCol, int* __restrict__ sRow, int* __restrict__ mpos)
{
  int tid = threadIdx.x;
  int d = blockIdx.x * 256 + tid;
  int base = blockSums[blockIdx.x];
  if (d < NN) {
    int o = dstOff[d] + base;
    dstOff[d] = o;
    dstCursor[d] = o + 1;
    sCol[NE + d] = d;
    sRow[NE + d] = d;
    mpos[NE + d] = o;
  }
  if (d == NN) dstOff[NN] = ET;
}

// fallback-mode self edges (no msg slots)
__global__ __launch_bounds__(256) void k_self0(int* __restrict__ sCol, int* __restrict__ sRow)
{
  int n = blockIdx.x * 256 + threadIdx.x;
  if (n < NN) { sCol[NE + n] = n; sRow[NE + n] = n; }
}

__global__ __launch_bounds__(256) void k_scatter(const int* __restrict__ ei, const int* __restrict__ et,
    int* __restrict__ meta, int* __restrict__ sCol, int* __restrict__ sRow,
    int* __restrict__ mpos, int* __restrict__ dstCursor, int doMsg)
{
  __shared__ int h[16], base[16], lh[16];
  int tid = threadIdx.x;
  int start = blockIdx.x * 4096;
  int end = min(NE, start + 4096);
  if (tid < 16) { h[tid] = 0; lh[tid] = 0; }
  __syncthreads();
  for (int e = start + tid; e < end; e += 256)
    atomicAdd(&h[et[e]], 1);
  __syncthreads();
  if (tid < 16) base[tid] = atomicAdd(&meta[CU0 + tid], h[tid]);
  __syncthreads();
  for (int e = start + tid; e < end; e += 256) {
    int r = et[e];
    int row = ei[e];
    int pos = base[r] + atomicAdd(&lh[r], 1);
    sCol[pos] = ei[NE + e];   // source (gather)
    sRow[pos] = row;          // destination
    if (doMsg) mpos[pos] = atomicAdd(&dstCursor[row], 1);
  }
}

// One 64-edge x 128-out tile per block. A: gathered x rows (bf16, LDS, padded units).
// B: wT[r] fragments in registers. D-layout: col=lane&15, row=quad*4+reg.
// msgmode 1: NT-write bf16 msg rows at dst-sorted slots. 0: atomic fallback.
// xbf 1: gather pre-cast bf16 xb. 0: gather fp32 x + convert.
__global__ __launch_bounds__(256) void k_gemm(const float* __restrict__ xf,
    const unsigned short* __restrict__ xb,
    const unsigned short* __restrict__ wT, const int* __restrict__ meta,
    const int* __restrict__ sCol, const int* __restrict__ sRow,
    const int* __restrict__ mpos, unsigned short* __restrict__ msg,
    float* __restrict__ out, int xbf, int msgmode)
{
  __shared__ short As[64 * 17 * 8];   // 17408 B
  __shared__ int Rows[64];
  __shared__ int Pos[64];
  int b = blockIdx.x;
  if (b >= meta[T0 + 17]) return;
  int r = 0;
  while (r < 16 && meta[T0 + r + 1] <= b) ++r;
  int tile = b - meta[T0 + r];
  int boff = meta[O0 + r];
  int bcnt = meta[C0 + r];
  int e0 = boff + tile * 64;
  int nrows = min(64, boff + bcnt - e0);

  int tid = threadIdx.x;
  int lane = tid & 63, wave = tid >> 6;
  int q = lane >> 4, l15 = lane & 15;

  // B fragments: wave owns cols [wave*32, wave*32+32)
  const unsigned short* wr = wT + r * 16384;
  short8 bf[2][4];
  #pragma unroll
  for (int ns = 0; ns < 2; ++ns) {
    #pragma unroll
    for (int kk = 0; kk < 4; ++kk) {
      int n = wave * 32 + ns * 16 + l15;
      bf[ns][kk] = *(const short8*)(wr + n * 128 + kk * 32 + q * 8);
    }
  }

  // Stage A: thread t -> row m = t>>2, quarter ug = t&3 (k in [ug*32, ug*32+32))
  int m = tid >> 2, ug = tid & 3;
  bool valid = m < nrows;
  int c = valid ? sCol[e0 + m] : 0;
  if (xbf) {
    const unsigned short* xr = xb + (size_t)c * 128;
    #pragma unroll
    for (int s = 0; s < 4; ++s) {
      int u = ug * 4 + s;
      short8 pk = (short8)(short)0;
      if (valid) pk = *(const short8*)(xr + u * 8);
      *(short8*)&As[(m * 17 + u) * 8] = pk;
    }
  } else {
    const float* xr = xf + (size_t)c * 128;
    #pragma unroll
    for (int s = 0; s < 4; ++s) {
      int u = ug * 4 + s;
      float4 f0 = make_float4(0.f, 0.f, 0.f, 0.f), f1 = f0;
      if (valid) {
        f0 = *(const float4*)(xr + u * 8);
        f1 = *(const float4*)(xr + u * 8 + 4);
      }
      short8 pk;
      pk[0] = (short)f2bf(f0.x); pk[1] = (short)f2bf(f0.y);
      pk[2] = (short)f2bf(f0.z); pk[3] = (short)f2bf(f0.w);
      pk[4] = (short)f2bf(f1.x); pk[5] = (short)f2bf(f1.y);
      pk[6] = (short)f2bf(f1.z); pk[7] = (short)f2bf(f1.w);
      *(short8*)&As[(m * 17 + u) * 8] = pk;
    }
  }
  if (tid < 64) {
    Rows[tid] = (tid < nrows) ? sRow[e0 + tid] : 0;
    Pos[tid] = (msgmode && tid < nrows) ? mpos[e0 + tid] : 0;
  }
  __syncthreads();

  f32x4 acc[4][2];
  #pragma unroll
  for (int ms = 0; ms < 4; ++ms)
    #pragma unroll
    for (int ns = 0; ns < 2; ++ns)
      acc[ms][ns] = (f32x4){0.f, 0.f, 0.f, 0.f};

  #pragma unroll
  for (int kk = 0; kk < 4; ++kk) {
    short8 af[4];
    #pragma unroll
    for (int ms = 0; ms < 4; ++ms)
      af[ms] = *(const short8*)&As[((ms * 16 + l15) * 17 + kk * 4 + q) * 8];
    #pragma unroll
    for (int ms = 0; ms < 4; ++ms)
      #pragma unroll
      for (int ns = 0; ns < 2; ++ns)
        acc[ms][ns] = __builtin_amdgcn_mfma_f32_16x16x32_bf16(af[ms], bf[ns][kk], acc[ms][ns], 0, 0, 0);
  }

  // Epilogue. D: col = lane&15, row = q*4 + reg.
  if (msgmode) {
    #pragma unroll
    for (int ms = 0; ms < 4; ++ms) {
      #pragma unroll
      for (int reg = 0; reg < 4; ++reg) {
        int mrow = ms * 16 + q * 4 + reg;
        if (mrow < nrows) {
          unsigned short* mp = msg + (size_t)Pos[mrow] * 128 + wave * 32 + l15;
          __builtin_nontemporal_store(f2bf(acc[ms][0][reg]), mp);
          __builtin_nontemporal_store(f2bf(acc[ms][1][reg]), mp + 16);
        }
      }
    }
  } else {
    #pragma unroll
    for (int ms = 0; ms < 4; ++ms) {
      #pragma unroll
      for (int reg = 0; reg < 4; ++reg) {
        int mrow = ms * 16 + q * 4 + reg;
        if (mrow < nrows) {
          float* op = out + (size_t)Rows[mrow] * 128 + wave * 32 + l15;
          unsafeAtomicAdd(op, acc[ms][0][reg]);
          unsafeAtomicAdd(op + 16, acc[ms][1][reg]);
        }
      }
    }
  }
}

// one wave per dst row: stream contiguous msg segment (NT), accumulate fp32, write once
__global__ __launch_bounds__(256) void k_reduce(const unsigned short* __restrict__ msg,
    const int* __restrict__ dstOff, float* __restrict__ out)
{
  int d = blockIdx.x * 4 + (threadIdx.x >> 6);
  if (d >= NN) return;
  int lane = threadIdx.x & 63;
  int s = dstOff[d], e = dstOff[d + 1];
  const unsigned int* base = (const unsigned int*)msg;
  float a0 = 0.f, a1 = 0.f, b0 = 0.f, b1 = 0.f;
  int j = s;
  for (; j + 1 < e; j += 2) {
    unsigned int v0 = __builtin_nontemporal_load(base + (size_t)j * 64 + lane);
    unsigned int v1 = __builtin_nontemporal_load(base + (size_t)(j + 1) * 64 + lane);
    a0 += __builtin_bit_cast(float, v0 << 16);
    a1 += __builtin_bit_cast(float, v0 & 0xffff0000u);
    b0 += __builtin_bit_cast(float, v1 << 16);
    b1 += __builtin_bit_cast(float, v1 & 0xffff0000u);
  }
  if (j < e) {
    unsigned int v0 = __builtin_nontemporal_load(base + (size_t)j * 64 + lane);
    a0 += __builtin_bit_cast(float, v0 << 16);
    a1 += __builtin_bit_cast(float, v0 & 0xffff0000u);
  }
  float2 w; w.x = a0 + b0; w.y = a1 + b1;
  *(float2*)(out + (size_t)d * 128 + lane * 2) = w;
}

extern "C" void kernel_launch(void* const* d_in, const int* in_sizes, int n_in,
                              void* d_out, int out_size, void* d_ws, size_t ws_size,
                              hipStream_t stream)
{
  const float* x      = (const float*)d_in[0];
  const int*   ei     = (const int*)d_in[1];
  const int*   et     = (const int*)d_in[2];
  const float* bases  = (const float*)d_in[3];
  const float* coef   = (const float*)d_in[4];
  const float* w_self = (const float*)d_in[5];
  float* out = (float*)d_out;
  char* ws = (char*)d_ws;
  unsigned short* wT = (unsigned short*)(ws + WT_OFF);
  int* meta      = (int*)(ws + META_OFF);
  int* dstHist   = (int*)(ws + DH_OFF);
  int* dstOff    = (int*)(ws + DO_OFF);
  int* dstCursor = (int*)(ws + DC_OFF);
  int* blockSums = (int*)(ws + BS_OFF);
  int* sCol      = (int*)(ws + SC_OFF);
  int* sRow      = (int*)(ws + SR_OFF);
  int* mpos      = (int*)(ws + MP_OFF);
  unsigned short* xb = (unsigned short*)(ws + XB_OFF);

  // mode selection is a pure function of ws_size (constant) -> graph-safe
  const int modeB = (ws_size >= NEED_B) ? 1 : 0;
  const int modeA = (modeB || ws_size >= NEED_A) ? 1 : 0;
  unsigned short* msg = (unsigned short*)(ws + (modeB ? MSGB_OFF : MSGA_OFF));

  // zero rel meta + dst histogram in one memset (contiguous)
  hipMemsetAsync(ws + META_OFF, 0, 512 + 400000, stream);
  k_weights<<<(17 * 16384) / 256, 256, 0, stream>>>(bases, coef, w_self, wT);
  if (modeB)
    k_xcast<<<(NN * D / 4 + 255) / 256, 256, 0, stream>>>(x, xb);
  k_hist<<<256, 256, 0, stream>>>(ei, et, meta, dstHist);
  if (modeA) {
    k_scan1<<<SCANB, 256, 0, stream>>>(dstHist, dstOff, blockSums);
    k_scan2<<<1, 512, 0, stream>>>(blockSums, meta);
    k_scan3<<<SCANB, 256, 0, stream>>>(dstOff, blockSums, dstCursor, sCol, sRow, mpos);
  } else {
    k_scan2<<<1, 512, 0, stream>>>(blockSums, meta);   // rel prefix only
    k_self0<<<SCANB, 256, 0, stream>>>(sCol, sRow);
    hipMemsetAsync(d_out, 0, (size_t)NN * D * 4, stream);
  }
  k_scatter<<<(NE + 4095) / 4096, 256, 0, stream>>>(ei, et, meta, sCol, sRow, mpos, dstCursor, modeA);
  // max tiles: sum_r ceil(c_r/64) + ceil(NN/64) <= 9391 + 1563 = 10954
  k_gemm<<<10954, 256, 0, stream>>>(x, xb, wT, meta, sCol, sRow, mpos, msg, out, modeB, modeA);
  if (modeA)
    k_reduce<<<(NN + 3) / 4, 256, 0, stream>>>(msg, dstOff, out);
}

// Round 4
// 334.009 us; speedup vs baseline: 1.2915x; 1.1721x over previous
//
#include <hip/hip_runtime.h>

#define NN 100000
#define NE 600000
#define ET (NE + NN)
#define D 128
#define NREL 16
#define SCANB 391   // 391*256 = 100096 >= NN
#define TPB 4       // tiles per gemm block
#define MAXTILES 10954
#define GEMMG ((MAXTILES + TPB - 1) / TPB)

typedef short short8 __attribute__((ext_vector_type(8)));
typedef float f32x4 __attribute__((ext_vector_type(4)));

// meta layout (ints)
#define C0 0    // counts[17]
#define O0 20   // offsets[18]
#define CU0 40  // cursors[17]
#define T0 60   // tileoff[18]

// ws layout (bytes)
#define WT_OFF   0                 // 17*128*128 bf16 = 557056
#define META_OFF 557056            // 512
#define DH_OFF   557568            // dstHist: 100000 ints
#define DO_OFF   957568            // dstOff: 100001 ints (pad to 400008)
#define DC_OFF   1357576           // dstCursor: 100000 ints
#define BS_OFF   1757576           // blockSums: 391 ints (pad 2000)
#define SCP_OFF  1759576           // sCP: 700064 int2 = 5600512
#define SR_OFF   7360088           // sRow (fallback only): 700000 ints
#define XB_OFF   10160096          // xb: 100000*128 bf16 = 25600000
#define MSGB_OFF 35760096          // msg (mode B)
#define MSGA_OFF 10160096          // msg (mode A, no xb)
#define NEED_B   (MSGB_OFF + (size_t)ET * 128 * 2)
#define NEED_A   (MSGA_OFF + (size_t)ET * 128 * 2)

__device__ __forceinline__ unsigned short f2bf(float f) {
  unsigned u = __builtin_bit_cast(unsigned, f);
  u += 0x7fffu + ((u >> 16) & 1u);   // RNE; inputs finite/normal
  return (unsigned short)(u >> 16);
}

// wT[r][o][i] = sum_b coef[r,b] * bases[b][i][o]  (bf16); slot 16 = w_self ([o][i])
__global__ __launch_bounds__(256) void k_weights(const float* __restrict__ bases,
    const float* __restrict__ coef, const float* __restrict__ w_self,
    unsigned short* __restrict__ wT)
{
  int idx = blockIdx.x * 256 + threadIdx.x;   // < 17*16384
  int r = idx >> 14;
  int t = idx & 16383;
  float v;
  if (r < 16) {
    int o = t >> 7, i = t & 127;
    float acc = 0.f;
    #pragma unroll
    for (int b = 0; b < 8; ++b)
      acc += coef[r * 8 + b] * bases[b * 16384 + i * 128 + o];
    v = acc;
  } else {
    v = w_self[t];
  }
  wT[idx] = f2bf(v);
}

// x (fp32) -> xb (bf16), 4 elems/thread
__global__ __launch_bounds__(256) void k_xcast(const float* __restrict__ x,
    unsigned short* __restrict__ xb)
{
  int i = blockIdx.x * 256 + threadIdx.x;   // < NN*D/4
  if (i >= NN * D / 4) return;
  float4 f = *(const float4*)(x + (size_t)i * 4);
  unsigned short s0 = f2bf(f.x), s1 = f2bf(f.y), s2 = f2bf(f.z), s3 = f2bf(f.w);
  unsigned long long pk = (unsigned long long)s0 | ((unsigned long long)s1 << 16)
                        | ((unsigned long long)s2 << 32) | ((unsigned long long)s3 << 48);
  *(unsigned long long*)(xb + (size_t)i * 4) = pk;
}

// rel histogram (LDS) + dst histogram (global atomics)
__global__ __launch_bounds__(256) void k_hist(const int* __restrict__ ei,
    const int* __restrict__ et, int* __restrict__ meta, int* __restrict__ dstHist)
{
  __shared__ int h[16];
  int tid = threadIdx.x;
  if (tid < 16) h[tid] = 0;
  __syncthreads();
  for (int e = blockIdx.x * 256 + tid; e < NE; e += gridDim.x * 256) {
    atomicAdd(&h[et[e]], 1);
    atomicAdd(&dstHist[ei[e]], 1);
  }
  __syncthreads();
  if (tid < 16) atomicAdd(&meta[C0 + tid], h[tid]);
}

// per-256-block local exclusive prefix of (dstHist[d]+1); block totals out
__global__ __launch_bounds__(256) void k_scan1(const int* __restrict__ dstHist,
    int* __restrict__ dstOff, int* __restrict__ blockSums)
{
  __shared__ int sh[256];
  int tid = threadIdx.x;
  int d = blockIdx.x * 256 + tid;
  int v = (d < NN) ? (dstHist[d] + 1) : 0;   // +1: virtual self edge
  sh[tid] = v;
  __syncthreads();
  #pragma unroll
  for (int ofs = 1; ofs < 256; ofs <<= 1) {
    int t = (tid >= ofs) ? sh[tid - ofs] : 0;
    __syncthreads();
    sh[tid] += t;
    __syncthreads();
  }
  if (d < NN) dstOff[d] = sh[tid] - v;       // local exclusive
  if (tid == 255) blockSums[blockIdx.x] = sh[tid];
}

// scan block totals; also fold the rel-prefix
__global__ __launch_bounds__(512) void k_scan2(int* __restrict__ blockSums, int* __restrict__ meta)
{
  __shared__ int sh[SCANB];
  int tid = threadIdx.x;
  if (tid < SCANB) sh[tid] = blockSums[tid];
  __syncthreads();
  if (tid == 0) {
    int run = 0;
    for (int i = 0; i < SCANB; ++i) { int c = sh[i]; sh[i] = run; run += c; }
    meta[C0 + 16] = NN;
    int off = 0, toff = 0;
    for (int r = 0; r <= 16; ++r) {
      meta[O0 + r] = off;
      meta[CU0 + r] = off;
      meta[T0 + r] = toff;
      int c = meta[C0 + r];
      off += c;
      toff += (c + 63) >> 6;
    }
    meta[O0 + 17] = off;
    meta[T0 + 17] = toff;
  }
  __syncthreads();
  if (tid < SCANB) blockSums[tid] = sh[tid];
}

// finalize dstOff; self edge claims slot 0 of each segment; cursor starts after.
__global__ __launch_bounds__(256) void k_scan3(int* __restrict__ dstOff,
    const int* __restrict__ blockSums, int* __restrict__ dstCursor,
    int2* __restrict__ sCP)
{
  int tid = threadIdx.x;
  int d = blockIdx.x * 256 + tid;
  int base = blockSums[blockIdx.x];
  if (d < NN) {
    int o = dstOff[d] + base;
    dstOff[d] = o;
    dstCursor[d] = o + 1;
    sCP[NE + d] = make_int2(d, o);
  }
  if (d == NN) dstOff[NN] = ET;
}

// fallback-mode self edges
__global__ __launch_bounds__(256) void k_self0(int2* __restrict__ sCP, int* __restrict__ sRow)
{
  int n = blockIdx.x * 256 + threadIdx.x;
  if (n < NN) { sCP[NE + n] = make_int2(n, 0); sRow[NE + n] = n; }
}

__global__ __launch_bounds__(256) void k_scatter(const int* __restrict__ ei, const int* __restrict__ et,
    int* __restrict__ meta, int2* __restrict__ sCP, int* __restrict__ sRow,
    int* __restrict__ dstCursor, int doMsg)
{
  __shared__ int h[16], base[16], lh[16];
  int tid = threadIdx.x;
  int start = blockIdx.x * 4096;
  int end = min(NE, start + 4096);
  if (tid < 16) { h[tid] = 0; lh[tid] = 0; }
  __syncthreads();
  for (int e = start + tid; e < end; e += 256)
    atomicAdd(&h[et[e]], 1);
  __syncthreads();
  if (tid < 16) base[tid] = atomicAdd(&meta[CU0 + tid], h[tid]);
  __syncthreads();
  for (int e = start + tid; e < end; e += 256) {
    int r = et[e];
    int row = ei[e];
    int pos = base[r] + atomicAdd(&lh[r], 1);
    int slot = doMsg ? atomicAdd(&dstCursor[row], 1) : 0;
    sCP[pos] = make_int2(ei[NE + e], slot);
    if (!doMsg) sRow[pos] = row;
  }
}

// TPB 64-edge x 128-out tiles per block. A: gathered rows (bf16 LDS, padded units).
// B: wT[r] frags in registers, reused while rel unchanged.
// msgmode 1: full-line msg-row stores via LDS transpose. 0: atomic fallback.
__global__ __launch_bounds__(256) void k_gemm(const float* __restrict__ xf,
    const unsigned short* __restrict__ xb,
    const unsigned short* __restrict__ wT, const int* __restrict__ meta,
    const int2* __restrict__ sCP, const int* __restrict__ sRow,
    unsigned short* __restrict__ msg, float* __restrict__ out,
    int xbf, int msgmode)
{
  __shared__ short As[64 * 17 * 8];   // 17408 B; staging, then epilogue transpose
  __shared__ int Pos[64];
  __shared__ int Rows[64];

  int ntiles = meta[T0 + 17];
  int tid = threadIdx.x;
  int lane = tid & 63, wave = tid >> 6;
  int q = lane >> 4, l15 = lane & 15;
  int m = tid >> 2, ug = tid & 3;     // staging: row m, quarter ug

  int rprev = -1;
  short8 bfr[2][4];

  for (int ti = 0; ti < TPB; ++ti) {
    int b = blockIdx.x * TPB + ti;
    if (b >= ntiles) break;
    int r = 0;
    while (r < 16 && meta[T0 + r + 1] <= b) ++r;
    int tile = b - meta[T0 + r];
    int boff = meta[O0 + r];
    int e0 = boff + tile * 64;
    int nrows = min(64, boff + meta[C0 + r] - e0);

    // ---- stage A tile ----
    bool valid = m < nrows;
    int e = valid ? (e0 + m) : e0;
    int2 cp = sCP[e];
    if (ug == 0) {
      Pos[m] = valid ? cp.y : 0;
      if (!msgmode) Rows[m] = valid ? sRow[e] : 0;
    }
    int c = cp.x;
    if (xbf) {
      const unsigned short* xr = xb + (size_t)c * 128;
      #pragma unroll
      for (int s = 0; s < 4; ++s) {
        int u = ug * 4 + s;
        short8 pk = (short8)(short)0;
        if (valid) pk = *(const short8*)(xr + u * 8);
        *(short8*)&As[(m * 17 + u) * 8] = pk;
      }
    } else {
      const float* xr = xf + (size_t)c * 128;
      #pragma unroll
      for (int s = 0; s < 4; ++s) {
        int u = ug * 4 + s;
        float4 f0 = make_float4(0.f, 0.f, 0.f, 0.f), f1 = f0;
        if (valid) {
          f0 = *(const float4*)(xr + u * 8);
          f1 = *(const float4*)(xr + u * 8 + 4);
        }
        short8 pk;
        pk[0] = (short)f2bf(f0.x); pk[1] = (short)f2bf(f0.y);
        pk[2] = (short)f2bf(f0.z); pk[3] = (short)f2bf(f0.w);
        pk[4] = (short)f2bf(f1.x); pk[5] = (short)f2bf(f1.y);
        pk[6] = (short)f2bf(f1.z); pk[7] = (short)f2bf(f1.w);
        *(short8*)&As[(m * 17 + u) * 8] = pk;
      }
    }
    __syncthreads();

    // ---- B frags (reload only on rel change) ----
    if (r != rprev) {
      const unsigned short* wr = wT + r * 16384;
      #pragma unroll
      for (int ns = 0; ns < 2; ++ns)
        #pragma unroll
        for (int kk = 0; kk < 4; ++kk)
          bfr[ns][kk] = *(const short8*)(wr + (wave * 32 + ns * 16 + l15) * 128 + kk * 32 + q * 8);
      rprev = r;
    }

    // ---- MFMA ----
    f32x4 acc[4][2];
    #pragma unroll
    for (int ms = 0; ms < 4; ++ms)
      #pragma unroll
      for (int ns = 0; ns < 2; ++ns)
        acc[ms][ns] = (f32x4){0.f, 0.f, 0.f, 0.f};
    #pragma unroll
    for (int kk = 0; kk < 4; ++kk) {
      short8 af[4];
      #pragma unroll
      for (int ms = 0; ms < 4; ++ms)
        af[ms] = *(const short8*)&As[((ms * 16 + l15) * 17 + kk * 4 + q) * 8];
      #pragma unroll
      for (int ms = 0; ms < 4; ++ms)
        #pragma unroll
        for (int ns = 0; ns < 2; ++ns)
          acc[ms][ns] = __builtin_amdgcn_mfma_f32_16x16x32_bf16(af[ms], bfr[ns][kk], acc[ms][ns], 0, 0, 0);
    }

    if (msgmode) {
      // ---- epilogue: acc -> LDS [64 rows][136 shorts], then full-row stores ----
      __syncthreads();   // As reads done; safe to overwrite
      #pragma unroll
      for (int ms = 0; ms < 4; ++ms)
        #pragma unroll
        for (int ns = 0; ns < 2; ++ns)
          #pragma unroll
          for (int reg = 0; reg < 4; ++reg)
            As[(ms * 16 + q * 4 + reg) * 136 + wave * 32 + ns * 16 + l15] =
                (short)f2bf(acc[ms][ns][reg]);
      __syncthreads();
      #pragma unroll
      for (int i = 0; i < 4; ++i) {
        int row = wave * 16 + i * 4 + (lane >> 4);
        short8 v = *(const short8*)&As[row * 136 + (lane & 15) * 8];
        if (row < nrows)
          *(short8*)(msg + (size_t)Pos[row] * 128 + (lane & 15) * 8) = v;
      }
      __syncthreads();   // protect As/Pos before next tile's staging
    } else {
      #pragma unroll
      for (int ms = 0; ms < 4; ++ms)
        #pragma unroll
        for (int reg = 0; reg < 4; ++reg) {
          int mrow = ms * 16 + q * 4 + reg;
          if (mrow < nrows) {
            float* op = out + (size_t)Rows[mrow] * 128 + wave * 32 + l15;
            unsafeAtomicAdd(op, acc[ms][0][reg]);
            unsafeAtomicAdd(op + 16, acc[ms][1][reg]);
          }
        }
      __syncthreads();
    }
  }
}

// one wave per dst row: stream contiguous msg segment, accumulate fp32, write once
__global__ __launch_bounds__(256) void k_reduce(const unsigned short* __restrict__ msg,
    const int* __restrict__ dstOff, float* __restrict__ out)
{
  int d = blockIdx.x * 4 + (threadIdx.x >> 6);
  if (d >= NN) return;
  int lane = threadIdx.x & 63;
  int s = dstOff[d], e = dstOff[d + 1];
  const unsigned int* base = (const unsigned int*)msg;
  float a0 = 0.f, a1 = 0.f, b0 = 0.f, b1 = 0.f;
  int j = s;
  for (; j + 1 < e; j += 2) {
    unsigned int v0 = base[(size_t)j * 64 + lane];
    unsigned int v1 = base[(size_t)(j + 1) * 64 + lane];
    a0 += __builtin_bit_cast(float, v0 << 16);
    a1 += __builtin_bit_cast(float, v0 & 0xffff0000u);
    b0 += __builtin_bit_cast(float, v1 << 16);
    b1 += __builtin_bit_cast(float, v1 & 0xffff0000u);
  }
  if (j < e) {
    unsigned int v0 = base[(size_t)j * 64 + lane];
    a0 += __builtin_bit_cast(float, v0 << 16);
    a1 += __builtin_bit_cast(float, v0 & 0xffff0000u);
  }
  float2 w; w.x = a0 + b0; w.y = a1 + b1;
  *(float2*)(out + (size_t)d * 128 + lane * 2) = w;
}

extern "C" void kernel_launch(void* const* d_in, const int* in_sizes, int n_in,
                              void* d_out, int out_size, void* d_ws, size_t ws_size,
                              hipStream_t stream)
{
  const float* x      = (const float*)d_in[0];
  const int*   ei     = (const int*)d_in[1];
  const int*   et     = (const int*)d_in[2];
  const float* bases  = (const float*)d_in[3];
  const float* coef   = (const float*)d_in[4];
  const float* w_self = (const float*)d_in[5];
  float* out = (float*)d_out;
  char* ws = (char*)d_ws;
  unsigned short* wT = (unsigned short*)(ws + WT_OFF);
  int* meta      = (int*)(ws + META_OFF);
  int* dstHist   = (int*)(ws + DH_OFF);
  int* dstOff    = (int*)(ws + DO_OFF);
  int* dstCursor = (int*)(ws + DC_OFF);
  int* blockSums = (int*)(ws + BS_OFF);
  int2* sCP      = (int2*)(ws + SCP_OFF);
  int* sRow      = (int*)(ws + SR_OFF);
  unsigned short* xb = (unsigned short*)(ws + XB_OFF);

  // mode selection is a pure function of ws_size -> graph-safe
  const int modeB = (ws_size >= NEED_B) ? 1 : 0;
  const int modeA = (modeB || ws_size >= NEED_A) ? 1 : 0;
  unsigned short* msg = (unsigned short*)(ws + (modeB ? MSGB_OFF : MSGA_OFF));

  hipMemsetAsync(ws + META_OFF, 0, 512 + 400000, stream);  // meta + dstHist
  k_weights<<<(17 * 16384) / 256, 256, 0, stream>>>(bases, coef, w_self, wT);
  if (modeB)
    k_xcast<<<(NN * D / 4 + 255) / 256, 256, 0, stream>>>(x, xb);
  k_hist<<<256, 256, 0, stream>>>(ei, et, meta, dstHist);
  if (modeA) {
    k_scan1<<<SCANB, 256, 0, stream>>>(dstHist, dstOff, blockSums);
    k_scan2<<<1, 512, 0, stream>>>(blockSums, meta);
    k_scan3<<<SCANB, 256, 0, stream>>>(dstOff, blockSums, dstCursor, sCP);
  } else {
    k_scan2<<<1, 512, 0, stream>>>(blockSums, meta);   // rel prefix only
    k_self0<<<SCANB, 256, 0, stream>>>(sCP, sRow);
    hipMemsetAsync(d_out, 0, (size_t)NN * D * 4, stream);
  }
  k_scatter<<<(NE + 4095) / 4096, 256, 0, stream>>>(ei, et, meta, sCP, sRow, dstCursor, modeA);
  k_gemm<<<GEMMG, 256, 0, stream>>>(x, xb, wT, meta, sCP, sRow, msg, out, modeB, modeA);
  if (modeA)
    k_reduce<<<(NN + 3) / 4, 256, 0, stream>>>(msg, dstOff, out);
}

// Round 5
// 329.525 us; speedup vs baseline: 1.3091x; 1.0136x over previous
//
#include <hip/hip_runtime.h>

#define NN 100000
#define NE 600000
#define ET (NE + NN)
#define D 128
#define NREL 16
#define SCANB 391   // 391*256 = 100096 >= NN
#define TPB 4       // tiles per gemm block
#define MAXTILES 10954
#define GEMMG ((MAXTILES + TPB - 1) / TPB)
#define WGRID 1088  // 17*16384/256

typedef short short8 __attribute__((ext_vector_type(8)));
typedef float f32x4 __attribute__((ext_vector_type(4)));
typedef unsigned int u32x4 __attribute__((ext_vector_type(4)));

// meta layout (ints)
#define C0 0    // counts[17]
#define O0 20   // offsets[18]
#define CU0 40  // cursors[17]
#define T0 60   // tileoff[18]

// ws layout (bytes)
#define WT_OFF   0                 // 17*128*128 bf16 = 557056
#define META_OFF 557056            // 512
#define DH_OFF   557568            // dstHist: 100000 ints
#define DO_OFF   957568            // dstOff: 100001 ints
#define DC_OFF   1357576           // dstCursor: 100000 ints
#define BS_OFF   1757576           // blockSums: 391 ints (pad)
#define SCP_OFF  1759576           // sCP: 700064 int2
#define SR_OFF   7360088           // sRow (fallback only): 700000 ints
#define XB_OFF   10160096          // xb: 100000*128 bf16
#define MSGB_OFF 35760096          // msg (mode B)
#define MSGA_OFF 10160096          // msg (mode A, no xb)
#define NEED_B   (MSGB_OFF + (size_t)ET * 128 * 2)
#define NEED_A   (MSGA_OFF + (size_t)ET * 128 * 2)

__device__ __forceinline__ unsigned short f2bf(float f) {
  unsigned u = __builtin_bit_cast(unsigned, f);
  u += 0x7fffu + ((u >> 16) & 1u);   // RNE; inputs finite/normal
  return (unsigned short)(u >> 16);
}

// blockIdx < WGRID: wT[r][o][i] = sum_b coef[r,b]*bases[b][i][o]; slot16 = w_self.
// else: x fp32 -> xb bf16 (4 elems/thread).
__global__ __launch_bounds__(256) void k_prep(const float* __restrict__ bases,
    const float* __restrict__ coef, const float* __restrict__ w_self,
    unsigned short* __restrict__ wT, const float* __restrict__ x,
    unsigned short* __restrict__ xb)
{
  if (blockIdx.x < WGRID) {
    int idx = blockIdx.x * 256 + threadIdx.x;   // < 17*16384
    int r = idx >> 14;
    int t = idx & 16383;
    float v;
    if (r < 16) {
      int o = t >> 7, i = t & 127;
      float acc = 0.f;
      #pragma unroll
      for (int b = 0; b < 8; ++b)
        acc += coef[r * 8 + b] * bases[b * 16384 + i * 128 + o];
      v = acc;
    } else {
      v = w_self[t];
    }
    wT[idx] = f2bf(v);
  } else {
    int i = (blockIdx.x - WGRID) * 256 + threadIdx.x;
    if (i >= NN * D / 4) return;
    float4 f = *(const float4*)(x + (size_t)i * 4);
    unsigned short s0 = f2bf(f.x), s1 = f2bf(f.y), s2 = f2bf(f.z), s3 = f2bf(f.w);
    unsigned long long pk = (unsigned long long)s0 | ((unsigned long long)s1 << 16)
                          | ((unsigned long long)s2 << 32) | ((unsigned long long)s3 << 48);
    *(unsigned long long*)(xb + (size_t)i * 4) = pk;
  }
}

// rel histogram (LDS) + dst histogram (global atomics)
__global__ __launch_bounds__(256) void k_hist(const int* __restrict__ ei,
    const int* __restrict__ et, int* __restrict__ meta, int* __restrict__ dstHist)
{
  __shared__ int h[16];
  int tid = threadIdx.x;
  if (tid < 16) h[tid] = 0;
  __syncthreads();
  for (int e = blockIdx.x * 256 + tid; e < NE; e += gridDim.x * 256) {
    atomicAdd(&h[et[e]], 1);
    atomicAdd(&dstHist[ei[e]], 1);
  }
  __syncthreads();
  if (tid < 16) atomicAdd(&meta[C0 + tid], h[tid]);
}

__global__ __launch_bounds__(256) void k_scan1(const int* __restrict__ dstHist,
    int* __restrict__ dstOff, int* __restrict__ blockSums)
{
  __shared__ int sh[256];
  int tid = threadIdx.x;
  int d = blockIdx.x * 256 + tid;
  int v = (d < NN) ? (dstHist[d] + 1) : 0;   // +1: virtual self edge
  sh[tid] = v;
  __syncthreads();
  #pragma unroll
  for (int ofs = 1; ofs < 256; ofs <<= 1) {
    int t = (tid >= ofs) ? sh[tid - ofs] : 0;
    __syncthreads();
    sh[tid] += t;
    __syncthreads();
  }
  if (d < NN) dstOff[d] = sh[tid] - v;
  if (tid == 255) blockSums[blockIdx.x] = sh[tid];
}

__global__ __launch_bounds__(512) void k_scan2(int* __restrict__ blockSums, int* __restrict__ meta)
{
  __shared__ int sh[SCANB];
  int tid = threadIdx.x;
  if (tid < SCANB) sh[tid] = blockSums[tid];
  __syncthreads();
  if (tid == 0) {
    int run = 0;
    for (int i = 0; i < SCANB; ++i) { int c = sh[i]; sh[i] = run; run += c; }
    meta[C0 + 16] = NN;
    int off = 0, toff = 0;
    for (int r = 0; r <= 16; ++r) {
      meta[O0 + r] = off;
      meta[CU0 + r] = off;
      meta[T0 + r] = toff;
      int c = meta[C0 + r];
      off += c;
      toff += (c + 63) >> 6;
    }
    meta[O0 + 17] = off;
    meta[T0 + 17] = toff;
  }
  __syncthreads();
  if (tid < SCANB) blockSums[tid] = sh[tid];
}

__global__ __launch_bounds__(256) void k_scan3(int* __restrict__ dstOff,
    const int* __restrict__ blockSums, int* __restrict__ dstCursor,
    int2* __restrict__ sCP)
{
  int tid = threadIdx.x;
  int d = blockIdx.x * 256 + tid;
  int base = blockSums[blockIdx.x];
  if (d < NN) {
    int o = dstOff[d] + base;
    dstOff[d] = o;
    dstCursor[d] = o + 1;
    sCP[NE + d] = make_int2(d, o);
  }
  if (d == NN) dstOff[NN] = ET;
}

__global__ __launch_bounds__(256) void k_self0(int2* __restrict__ sCP, int* __restrict__ sRow)
{
  int n = blockIdx.x * 256 + threadIdx.x;
  if (n < NN) { sCP[NE + n] = make_int2(n, 0); sRow[NE + n] = n; }
}

__global__ __launch_bounds__(256) void k_scatter(const int* __restrict__ ei, const int* __restrict__ et,
    int* __restrict__ meta, int2* __restrict__ sCP, int* __restrict__ sRow,
    int* __restrict__ dstCursor, int doMsg)
{
  __shared__ int h[16], base[16], lh[16];
  int tid = threadIdx.x;
  int start = blockIdx.x * 4096;
  int end = min(NE, start + 4096);
  if (tid < 16) { h[tid] = 0; lh[tid] = 0; }
  __syncthreads();
  for (int e = start + tid; e < end; e += 256)
    atomicAdd(&h[et[e]], 1);
  __syncthreads();
  if (tid < 16) base[tid] = atomicAdd(&meta[CU0 + tid], h[tid]);
  __syncthreads();
  for (int e = start + tid; e < end; e += 256) {
    int r = et[e];
    int row = ei[e];
    int pos = base[r] + atomicAdd(&lh[r], 1);
    int slot = doMsg ? atomicAdd(&dstCursor[row], 1) : 0;
    sCP[pos] = make_int2(ei[NE + e], slot);
    if (!doMsg) sRow[pos] = row;
  }
}

// TPB tiles/block. Fast path (xbf&&msgmode): 2 barriers/tile, register prefetch
// of next tile's gather overlapping MFMA+epilogue. Generic fallback: R4 code.
__global__ __launch_bounds__(256) void k_gemm(const float* __restrict__ xf,
    const unsigned short* __restrict__ xb,
    const unsigned short* __restrict__ wT, const int* __restrict__ meta,
    const int2* __restrict__ sCP, const int* __restrict__ sRow,
    unsigned short* __restrict__ msg, float* __restrict__ out,
    int xbf, int msgmode)
{
  __shared__ short As[64 * 17 * 8];   // staging (8704 shorts; fallback reuses for transpose)
  __shared__ short Es[64 * 136];      // epilogue rows
  __shared__ int Pos2[2][64];
  __shared__ int Rows[64];
  __shared__ int Ms[80];

  int tid = threadIdx.x;
  if (tid < 80) Ms[tid] = meta[tid];
  __syncthreads();
  int ntiles = Ms[T0 + 17];

  int lane = tid & 63, wave = tid >> 6;
  int q = lane >> 4, l15 = lane & 15;
  int m = tid >> 2, ug = tid & 3;

  if (xbf && msgmode) {
    short8 pf[4];
    int pcy = 0;
    bool pvalid = false;
    int r = 0, nr = 0;
    int b = blockIdx.x * TPB;
    if (b < ntiles) {
      while (r < 16 && Ms[T0 + r + 1] <= b) ++r;
      int boff = Ms[O0 + r];
      int e0 = boff + (b - Ms[T0 + r]) * 64;
      nr = min(64, boff + Ms[C0 + r] - e0);
      pvalid = m < nr;
      int2 cp = sCP[pvalid ? (e0 + m) : e0];
      pcy = cp.y;
      const unsigned short* xr = xb + (size_t)cp.x * 128;
      #pragma unroll
      for (int s = 0; s < 4; ++s) {
        short8 v = (short8)(short)0;
        if (pvalid) v = *(const short8*)(xr + (ug * 4 + s) * 8);
        pf[s] = v;
      }
    }
    int rprev = -1;
    short8 bfr[2][4];
    for (int ti = 0; ti < TPB; ++ti) {
      b = blockIdx.x * TPB + ti;
      if (b >= ntiles) break;
      int curR = r, curNr = nr;
      // ---- staging store from prefetched regs ----
      #pragma unroll
      for (int s = 0; s < 4; ++s)
        *(short8*)&As[(m * 17 + ug * 4 + s) * 8] = pf[s];
      if (ug == 0) Pos2[ti & 1][m] = pvalid ? pcy : 0;
      __syncthreads();   // sync1: staging visible; drains prior Es/Pos reads
      // ---- prefetch next tile (overlaps MFMA+epilogue) ----
      int bn = b + 1;
      if (ti + 1 < TPB && bn < ntiles) {
        int rn = curR;
        while (rn < 16 && Ms[T0 + rn + 1] <= bn) ++rn;
        int boff = Ms[O0 + rn];
        int e0n = boff + (bn - Ms[T0 + rn]) * 64;
        int nrn = min(64, boff + Ms[C0 + rn] - e0n);
        pvalid = m < nrn;
        int2 cp = sCP[pvalid ? (e0n + m) : e0n];
        pcy = cp.y;
        const unsigned short* xr = xb + (size_t)cp.x * 128;
        #pragma unroll
        for (int s = 0; s < 4; ++s) {
          short8 v = (short8)(short)0;
          if (pvalid) v = *(const short8*)(xr + (ug * 4 + s) * 8);
          pf[s] = v;
        }
        r = rn; nr = nrn;
      }
      // ---- B frags (reload only on rel change) ----
      if (curR != rprev) {
        const unsigned short* wr = wT + curR * 16384;
        #pragma unroll
        for (int ns = 0; ns < 2; ++ns)
          #pragma unroll
          for (int kk = 0; kk < 4; ++kk)
            bfr[ns][kk] = *(const short8*)(wr + (wave * 32 + ns * 16 + l15) * 128 + kk * 32 + q * 8);
        rprev = curR;
      }
      // ---- MFMA ----
      f32x4 acc[4][2];
      #pragma unroll
      for (int ms = 0; ms < 4; ++ms)
        #pragma unroll
        for (int ns = 0; ns < 2; ++ns)
          acc[ms][ns] = (f32x4){0.f, 0.f, 0.f, 0.f};
      #pragma unroll
      for (int kk = 0; kk < 4; ++kk) {
        short8 af[4];
        #pragma unroll
        for (int ms = 0; ms < 4; ++ms)
          af[ms] = *(const short8*)&As[((ms * 16 + l15) * 17 + kk * 4 + q) * 8];
        #pragma unroll
        for (int ms = 0; ms < 4; ++ms)
          #pragma unroll
          for (int ns = 0; ns < 2; ++ns)
            acc[ms][ns] = __builtin_amdgcn_mfma_f32_16x16x32_bf16(af[ms], bfr[ns][kk], acc[ms][ns], 0, 0, 0);
      }
      // ---- transpose to Es ----
      #pragma unroll
      for (int ms = 0; ms < 4; ++ms)
        #pragma unroll
        for (int ns = 0; ns < 2; ++ns)
          #pragma unroll
          for (int reg = 0; reg < 4; ++reg)
            Es[(ms * 16 + q * 4 + reg) * 136 + wave * 32 + ns * 16 + l15] =
                (short)f2bf(acc[ms][ns][reg]);
      __syncthreads();   // sync2: Es visible; MFMA As-reads drained
      // ---- full-row msg stores ----
      #pragma unroll
      for (int i = 0; i < 4; ++i) {
        int row = wave * 16 + i * 4 + q;
        short8 v = *(const short8*)&Es[row * 136 + l15 * 8];
        if (row < curNr)
          *(short8*)(msg + (size_t)Pos2[ti & 1][row] * 128 + l15 * 8) = v;
      }
    }
    return;
  }

  // ---------------- generic fallback (R4-validated) ----------------
  int rprev = -1;
  short8 bfr[2][4];
  for (int ti = 0; ti < TPB; ++ti) {
    int b = blockIdx.x * TPB + ti;
    if (b >= ntiles) break;
    int r = 0;
    while (r < 16 && Ms[T0 + r + 1] <= b) ++r;
    int tile = b - Ms[T0 + r];
    int boff = Ms[O0 + r];
    int e0 = boff + tile * 64;
    int nrows = min(64, boff + Ms[C0 + r] - e0);

    bool valid = m < nrows;
    int e = valid ? (e0 + m) : e0;
    int2 cp = sCP[e];
    if (ug == 0) {
      Pos2[0][m] = valid ? cp.y : 0;
      if (!msgmode) Rows[m] = valid ? sRow[e] : 0;
    }
    int c = cp.x;
    if (xbf) {
      const unsigned short* xr = xb + (size_t)c * 128;
      #pragma unroll
      for (int s = 0; s < 4; ++s) {
        int u = ug * 4 + s;
        short8 pk = (short8)(short)0;
        if (valid) pk = *(const short8*)(xr + u * 8);
        *(short8*)&As[(m * 17 + u) * 8] = pk;
      }
    } else {
      const float* xr = xf + (size_t)c * 128;
      #pragma unroll
      for (int s = 0; s < 4; ++s) {
        int u = ug * 4 + s;
        float4 f0 = make_float4(0.f, 0.f, 0.f, 0.f), f1 = f0;
        if (valid) {
          f0 = *(const float4*)(xr + u * 8);
          f1 = *(const float4*)(xr + u * 8 + 4);
        }
        short8 pk;
        pk[0] = (short)f2bf(f0.x); pk[1] = (short)f2bf(f0.y);
        pk[2] = (short)f2bf(f0.z); pk[3] = (short)f2bf(f0.w);
        pk[4] = (short)f2bf(f1.x); pk[5] = (short)f2bf(f1.y);
        pk[6] = (short)f2bf(f1.z); pk[7] = (short)f2bf(f1.w);
        *(short8*)&As[(m * 17 + u) * 8] = pk;
      }
    }
    __syncthreads();

    if (r != rprev) {
      const unsigned short* wr = wT + r * 16384;
      #pragma unroll
      for (int ns = 0; ns < 2; ++ns)
        #pragma unroll
        for (int kk = 0; kk < 4; ++kk)
          bfr[ns][kk] = *(const short8*)(wr + (wave * 32 + ns * 16 + l15) * 128 + kk * 32 + q * 8);
      rprev = r;
    }

    f32x4 acc[4][2];
    #pragma unroll
    for (int ms = 0; ms < 4; ++ms)
      #pragma unroll
      for (int ns = 0; ns < 2; ++ns)
        acc[ms][ns] = (f32x4){0.f, 0.f, 0.f, 0.f};
    #pragma unroll
    for (int kk = 0; kk < 4; ++kk) {
      short8 af[4];
      #pragma unroll
      for (int ms = 0; ms < 4; ++ms)
        af[ms] = *(const short8*)&As[((ms * 16 + l15) * 17 + kk * 4 + q) * 8];
      #pragma unroll
      for (int ms = 0; ms < 4; ++ms)
        #pragma unroll
        for (int ns = 0; ns < 2; ++ns)
          acc[ms][ns] = __builtin_amdgcn_mfma_f32_16x16x32_bf16(af[ms], bfr[ns][kk], acc[ms][ns], 0, 0, 0);
    }

    if (msgmode) {
      __syncthreads();
      #pragma unroll
      for (int ms = 0; ms < 4; ++ms)
        #pragma unroll
        for (int ns = 0; ns < 2; ++ns)
          #pragma unroll
          for (int reg = 0; reg < 4; ++reg)
            Es[(ms * 16 + q * 4 + reg) * 136 + wave * 32 + ns * 16 + l15] =
                (short)f2bf(acc[ms][ns][reg]);
      __syncthreads();
      #pragma unroll
      for (int i = 0; i < 4; ++i) {
        int row = wave * 16 + i * 4 + q;
        short8 v = *(const short8*)&Es[row * 136 + l15 * 8];
        if (row < nrows)
          *(short8*)(msg + (size_t)Pos2[0][row] * 128 + l15 * 8) = v;
      }
      __syncthreads();
    } else {
      #pragma unroll
      for (int ms = 0; ms < 4; ++ms)
        #pragma unroll
        for (int reg = 0; reg < 4; ++reg) {
          int mrow = ms * 16 + q * 4 + reg;
          if (mrow < nrows) {
            float* op = out + (size_t)Rows[mrow] * 128 + wave * 32 + l15;
            unsafeAtomicAdd(op, acc[ms][0][reg]);
            unsafeAtomicAdd(op + 16, acc[ms][1][reg]);
          }
        }
      __syncthreads();
    }
  }
}

// one 16-lane group per dst (4 dsts/wave): dwordx4 row loads, fp32 accumulate, one store
__global__ __launch_bounds__(256) void k_reduce(const unsigned short* __restrict__ msg,
    const int* __restrict__ dstOff, float* __restrict__ out)
{
  int d = blockIdx.x * 16 + (threadIdx.x >> 4);
  if (d >= NN) return;
  int sl = threadIdx.x & 15;
  int s = dstOff[d], e = dstOff[d + 1];
  const unsigned short* base = msg + (size_t)sl * 8;
  float a[8], bacc[8];
  #pragma unroll
  for (int i = 0; i < 8; ++i) { a[i] = 0.f; bacc[i] = 0.f; }
  int j = s;
  for (; j + 1 < e; j += 2) {
    u32x4 v0 = *(const u32x4*)(base + (size_t)j * 128);
    u32x4 v1 = *(const u32x4*)(base + (size_t)(j + 1) * 128);
    #pragma unroll
    for (int c = 0; c < 4; ++c) {
      a[2 * c]     += __builtin_bit_cast(float, v0[c] << 16);
      a[2 * c + 1] += __builtin_bit_cast(float, v0[c] & 0xffff0000u);
      bacc[2 * c]     += __builtin_bit_cast(float, v1[c] << 16);
      bacc[2 * c + 1] += __builtin_bit_cast(float, v1[c] & 0xffff0000u);
    }
  }
  if (j < e) {
    u32x4 v0 = *(const u32x4*)(base + (size_t)j * 128);
    #pragma unroll
    for (int c = 0; c < 4; ++c) {
      a[2 * c]     += __builtin_bit_cast(float, v0[c] << 16);
      a[2 * c + 1] += __builtin_bit_cast(float, v0[c] & 0xffff0000u);
    }
  }
  float4 w0, w1;
  w0.x = a[0] + bacc[0]; w0.y = a[1] + bacc[1]; w0.z = a[2] + bacc[2]; w0.w = a[3] + bacc[3];
  w1.x = a[4] + bacc[4]; w1.y = a[5] + bacc[5]; w1.z = a[6] + bacc[6]; w1.w = a[7] + bacc[7];
  float* op = out + (size_t)d * 128 + sl * 8;
  *(float4*)op = w0;
  *(float4*)(op + 4) = w1;
}

extern "C" void kernel_launch(void* const* d_in, const int* in_sizes, int n_in,
                              void* d_out, int out_size, void* d_ws, size_t ws_size,
                              hipStream_t stream)
{
  const float* x      = (const float*)d_in[0];
  const int*   ei     = (const int*)d_in[1];
  const int*   et     = (const int*)d_in[2];
  const float* bases  = (const float*)d_in[3];
  const float* coef   = (const float*)d_in[4];
  const float* w_self = (const float*)d_in[5];
  float* out = (float*)d_out;
  char* ws = (char*)d_ws;
  unsigned short* wT = (unsigned short*)(ws + WT_OFF);
  int* meta      = (int*)(ws + META_OFF);
  int* dstHist   = (int*)(ws + DH_OFF);
  int* dstOff    = (int*)(ws + DO_OFF);
  int* dstCursor = (int*)(ws + DC_OFF);
  int* blockSums = (int*)(ws + BS_OFF);
  int2* sCP      = (int2*)(ws + SCP_OFF);
  int* sRow      = (int*)(ws + SR_OFF);
  unsigned short* xb = (unsigned short*)(ws + XB_OFF);

  const int modeB = (ws_size >= NEED_B) ? 1 : 0;
  const int modeA = (modeB || ws_size >= NEED_A) ? 1 : 0;
  unsigned short* msg = (unsigned short*)(ws + (modeB ? MSGB_OFF : MSGA_OFF));

  hipMemsetAsync(ws + META_OFF, 0, 512 + 400000, stream);  // meta + dstHist
  k_prep<<<modeB ? (WGRID + 12500) : WGRID, 256, 0, stream>>>(bases, coef, w_self, wT, x, xb);
  k_hist<<<256, 256, 0, stream>>>(ei, et, meta, dstHist);
  if (modeA) {
    k_scan1<<<SCANB, 256, 0, stream>>>(dstHist, dstOff, blockSums);
    k_scan2<<<1, 512, 0, stream>>>(blockSums, meta);
    k_scan3<<<SCANB, 256, 0, stream>>>(dstOff, blockSums, dstCursor, sCP);
  } else {
    k_scan2<<<1, 512, 0, stream>>>(blockSums, meta);
    k_self0<<<SCANB, 256, 0, stream>>>(sCP, sRow);
    hipMemsetAsync(d_out, 0, (size_t)NN * D * 4, stream);
  }
  k_scatter<<<(NE + 4095) / 4096, 256, 0, stream>>>(ei, et, meta, sCP, sRow, dstCursor, modeA);
  k_gemm<<<GEMMG, 256, 0, stream>>>(x, xb, wT, meta, sCP, sRow, msg, out, modeB, modeA);
  if (modeA)
    k_reduce<<<(NN + 15) / 16, 256, 0, stream>>>(msg, dstOff, out);
}